// Round 7
// baseline (307.901 us; speedup 1.0000x reference)
//
#include <hip/hip_runtime.h>
#include <hip/hip_bf16.h>
#include <math.h>

#define N_NODES 50000
#define IN_DIM 256
#define OUT_DIM 128
#define NUM_HEADS 2
#define N_EDGES 800000
#define F (OUT_DIM*NUM_HEADS)   /* 256 */
#define SCAN_B 1024
#define N_SB ((N_NODES + SCAN_B - 1) / SCAN_B)   /* 49 */
#define LDSP 264                 /* 256 + 8 pad: row stride 528B = 132w = 4 mod 32 banks */

typedef __bf16 bf16;
typedef __bf16 bf16x8 __attribute__((ext_vector_type(8)));
typedef __bf16 bf16x4 __attribute__((ext_vector_type(4)));
typedef float  f32x4  __attribute__((ext_vector_type(4)));

// ---------------- K0: W -> Wt (bf16, transposed) + zero deg --------------
__global__ void k_transpose(const float* __restrict__ W, bf16* __restrict__ Wt,
                            int* __restrict__ deg) {
    int k = blockIdx.x;      // 0..IN_DIM-1
    int n = threadIdx.x;     // 0..F-1
    Wt[(size_t)n*IN_DIM + k] = (bf16)W[(size_t)k*F + n];
    int id = blockIdx.x * F + threadIdx.x;
    if (id < N_NODES) deg[id] = 0;
}

// ---------------- K1: Wh = x @ W + b  (MFMA bf16, full-K LDS A-tile) -----
// Block: 64 rows x 256 cols, 4 waves (wave w: cols [64w,64w+64)).
// Stage all K=256 of A once (16 indep f32x4 loads/thread), ONE barrier,
// then 8 K-steps of pure ds_read_b128 + MFMA.
__global__ __launch_bounds__(256) void k_gemm(const float* __restrict__ X,
                                              const bf16* __restrict__ Wt,
                                              const float* __restrict__ Wb,
                                              bf16* __restrict__ Wh) {
    __shared__ bf16 As[64 * LDSP];
    int t = threadIdx.x;
    int wave = t >> 6, lane = t & 63;
    int quad = lane >> 4, l16 = lane & 15;
    int row0 = blockIdx.x * 64;
    int col0 = wave * 64;

    // staging: thread t, chunk i (i<8): row = 8i + (t>>5), cols (t&31)*8..+8
    {
        int rr = t >> 5;          // 0..7
        int cc = (t & 31) * 8;    // 0..248
        #pragma unroll
        for (int i = 0; i < 8; ++i) {
            int r = row0 + 8*i + rr;
            r = (r < N_NODES) ? r : (N_NODES - 1);      // clamp; stores masked
            const float* p = X + (size_t)r * IN_DIM + cc;
            f32x4 lo = *(const f32x4*)p;
            f32x4 hi = *(const f32x4*)(p + 4);
            bf16x8 pk;
            #pragma unroll
            for (int q = 0; q < 4; ++q) {
                pk[q]   = (bf16)lo[q];
                pk[q+4] = (bf16)hi[q];
            }
            *(bf16x8*)(As + (8*i + rr) * LDSP + cc) = pk;
        }
    }
    __syncthreads();

    f32x4 acc[4][4] = {};
    #pragma unroll
    for (int ks = 0; ks < 8; ++ks) {
        int kb = ks * 32;
        bf16x8 bfrag[4];
        #pragma unroll
        for (int ni = 0; ni < 4; ++ni)
            bfrag[ni] = *(const bf16x8*)(Wt + (size_t)(col0 + ni*16 + l16)*IN_DIM
                                            + kb + quad*8);
        bf16x8 afrag[4];
        #pragma unroll
        for (int mi = 0; mi < 4; ++mi)
            afrag[mi] = *(const bf16x8*)(As + (mi*16 + l16)*LDSP + kb + quad*8);

        #pragma unroll
        for (int mi = 0; mi < 4; ++mi)
            #pragma unroll
            for (int ni = 0; ni < 4; ++ni)
                acc[mi][ni] = __builtin_amdgcn_mfma_f32_16x16x32_bf16(
                                  afrag[mi], bfrag[ni], acc[mi][ni], 0, 0, 0);
    }
    // epilogue: C/D layout col = lane&15, row = quad*4 + reg
    #pragma unroll
    for (int mi = 0; mi < 4; ++mi) {
        #pragma unroll
        for (int ni = 0; ni < 4; ++ni) {
            int c = col0 + ni*16 + l16;
            float bias = Wb[c];
            #pragma unroll
            for (int reg = 0; reg < 4; ++reg) {
                int row = row0 + mi*16 + quad*4 + reg;
                if (row < N_NODES)
                    Wh[(size_t)row*F + c] = (bf16)(acc[mi][ni][reg] + bias);
            }
        }
    }
}

// ---------------- K2: s,t = Wh · a_src, Wh · a_dst ----------------
__global__ __launch_bounds__(256) void k_st(const bf16* __restrict__ Wh,
                                            const float* __restrict__ a,
                                            float* __restrict__ s_arr,
                                            float* __restrict__ t_arr) {
    int wave = threadIdx.x >> 6, lane = threadIdx.x & 63;
    int n = blockIdx.x * 4 + wave;
    int c = lane * 4;
    int d = c & (OUT_DIM - 1);
    int h = c >> 7;
    bf16x4 wh = *(const bf16x4*)(Wh + (size_t)n*F + c);
    f32x4 as = *(const f32x4*)(a + d);
    f32x4 ad = *(const f32x4*)(a + OUT_DIM + d);
    float ps = 0.f, pt = 0.f;
    #pragma unroll
    for (int i = 0; i < 4; ++i) {
        float w = (float)wh[i];
        ps += w * as[i];
        pt += w * ad[i];
    }
    #pragma unroll
    for (int m = 16; m >= 1; m >>= 1) {
        ps += __shfl_xor(ps, m);
        pt += __shfl_xor(pt, m);
    }
    if ((lane & 31) == 0) {
        s_arr[n*2 + h] = ps;
        t_arr[n*2 + h] = pt;
    }
}

// ---------------- K3: degree histogram over src ----------------
__global__ void k_hist(const int* __restrict__ src, int* __restrict__ deg) {
    int e = blockIdx.x * 256 + threadIdx.x;
    if (e < N_EDGES) atomicAdd(&deg[src[e]], 1);
}

// ---------------- K4a: per-block inclusive scan ----------------
__global__ __launch_bounds__(SCAN_B) void k_scan_local(const int* __restrict__ deg,
                                                       int* __restrict__ incl,
                                                       int* __restrict__ bsum) {
    __shared__ int lds[SCAN_B];
    int t = threadIdx.x;
    int i = blockIdx.x * SCAN_B + t;
    int v = (i < N_NODES) ? deg[i] : 0;
    lds[t] = v;
    __syncthreads();
    for (int off = 1; off < SCAN_B; off <<= 1) {
        int u = (t >= off) ? lds[t - off] : 0;
        __syncthreads();
        lds[t] += u;
        __syncthreads();
    }
    if (i < N_NODES) incl[i] = lds[t];
    if (t == SCAN_B - 1) bsum[blockIdx.x] = lds[t];
}

// ---------------- K4b: scan the 49 block sums (one wave) ----------------
__global__ __launch_bounds__(64) void k_scan_block(const int* __restrict__ bsum,
                                                   int* __restrict__ boff,
                                                   int* __restrict__ row_start) {
    int t = threadIdx.x;
    int orig = (t < N_SB) ? bsum[t] : 0;
    int v = orig;
    #pragma unroll
    for (int off = 1; off < 64; off <<= 1) {
        int u = __shfl_up(v, off);
        if (t >= off) v += u;
    }
    if (t < N_SB) boff[t] = v - orig;
    if (t == 63) row_start[N_NODES] = v;
}

// ---------------- K4c: finalize exclusive scan ----------------
__global__ __launch_bounds__(256) void k_scan_final(const int* __restrict__ incl,
                                                    const int* __restrict__ deg,
                                                    const int* __restrict__ boff,
                                                    int* __restrict__ row_start,
                                                    int* __restrict__ cursor) {
    int i = blockIdx.x * 256 + threadIdx.x;
    if (i < N_NODES) {
        int excl = incl[i] - deg[i] + boff[i >> 10];
        row_start[i] = excl;
        cursor[i]    = excl;
    }
}

// ---------------- K5: scatter edges into CSR slots (grouped by src) ------
__global__ void k_scatter(const int* __restrict__ src, const int* __restrict__ dst,
                          int* __restrict__ cursor, int* __restrict__ sorted_dst) {
    int e = blockIdx.x * 256 + threadIdx.x;
    if (e < N_EDGES) {
        int s = src[e];
        int pos = atomicAdd(&cursor[s], 1);
        sorted_dst[pos] = dst[e];
    }
}

// ---------------- K6a: per-edge softmax weights (unnormalized) -----------
__global__ __launch_bounds__(256) void k_alpha(const float* __restrict__ s_arr,
                                               const float* __restrict__ t_arr,
                                               const int* __restrict__ row_start,
                                               const int* __restrict__ sdst,
                                               float* __restrict__ palpha,
                                               float* __restrict__ dinv) {
    int wave = threadIdx.x >> 6, lane = threadIdx.x & 63;
    int n = blockIdx.x * 4 + wave;
    int h = lane >> 5;
    int sl = lane & 31;
    int beg = row_start[n], end = row_start[n + 1];
    int deg = end - beg;
    if (deg == 0) return;
    float s = s_arr[n*2 + h];
    float* pa = palpha + (size_t)h * N_EDGES;

    float e0 = -INFINITY;
    if (sl < deg) {
        int d = sdst[beg + sl];
        float e = s + t_arr[d*2 + h];
        e0 = (e >= 0.f) ? e : 0.2f * e;
    }
    float mx = e0;
    for (int j0 = 32; j0 < deg; j0 += 32) {
        int jj = j0 + sl;
        if (jj < deg) {
            int d = sdst[beg + jj];
            float e = s + t_arr[d*2 + h];
            e = (e >= 0.f) ? e : 0.2f * e;
            mx = fmaxf(mx, e);
        }
    }
    #pragma unroll
    for (int m = 16; m >= 1; m >>= 1) mx = fmaxf(mx, __shfl_xor(mx, m));

    float p0 = (sl < deg) ? __expf(e0 - mx) : 0.f;
    if (sl < deg) pa[beg + sl] = p0;
    float sum = p0;
    for (int j0 = 32; j0 < deg; j0 += 32) {
        int jj = j0 + sl;
        float p = 0.f;
        if (jj < deg) {
            int d = sdst[beg + jj];
            float e = s + t_arr[d*2 + h];
            e = (e >= 0.f) ? e : 0.2f * e;
            p = __expf(e - mx);
            pa[beg + jj] = p;
        }
        sum += p;
    }
    #pragma unroll
    for (int m = 16; m >= 1; m >>= 1) sum += __shfl_xor(sum, m);
    if (sl == 0) dinv[n*2 + h] = 1.f / sum;
}

// ---------------- K6b: gather+FMA aggregation, 8 edges/iter --------------
// wave per node; lane l: edge-slot sub = l>>5, col-group c = (l&31)*8 (16B/lane).
__global__ __launch_bounds__(256) void k_agg2(const bf16* __restrict__ Wh,
                                              const float* __restrict__ palpha,
                                              const float* __restrict__ dinv,
                                              const int* __restrict__ row_start,
                                              const int* __restrict__ sorted_dst,
                                              float* __restrict__ out) {
    int wave = threadIdx.x >> 6, lane = threadIdx.x & 63;
    int n = blockIdx.x * 4 + wave;
    int sub = lane >> 5;
    int cl  = lane & 31;
    int c   = cl * 8;
    int h   = c >> 7;
    int beg = row_start[n], end = row_start[n + 1];
    if (beg == end) {   // isolated node: h' = Wh
        if (sub == 0) {
            bf16x8 wh = *(const bf16x8*)(Wh + (size_t)n*F + c);
            f32x4 o0, o1;
            #pragma unroll
            for (int i = 0; i < 4; ++i) { o0[i] = (float)wh[i]; o1[i] = (float)wh[4+i]; }
            *(f32x4*)(out + (size_t)n*F + c)     = o0;
            *(f32x4*)(out + (size_t)n*F + c + 4) = o1;
        }
        return;
    }
    const float* pa = palpha + (size_t)h * N_EDGES;
    float a[8] = {0,0,0,0,0,0,0,0};
    float b[8] = {0,0,0,0,0,0,0,0};
    int j = beg;
    for (; j + 8 <= end; j += 8) {          // 8 edges/iter: 4 indep loads/lane
        int   jj0 = j + sub,     jj1 = j + 2 + sub;
        int   jj2 = j + 4 + sub, jj3 = j + 6 + sub;
        int   d0 = sorted_dst[jj0], d1 = sorted_dst[jj1];
        int   d2 = sorted_dst[jj2], d3 = sorted_dst[jj3];
        float p0 = pa[jj0], p1 = pa[jj1], p2 = pa[jj2], p3 = pa[jj3];
        bf16x8 w0 = *(const bf16x8*)(Wh + (size_t)d0*F + c);
        bf16x8 w1 = *(const bf16x8*)(Wh + (size_t)d1*F + c);
        bf16x8 w2 = *(const bf16x8*)(Wh + (size_t)d2*F + c);
        bf16x8 w3 = *(const bf16x8*)(Wh + (size_t)d3*F + c);
        #pragma unroll
        for (int i = 0; i < 8; ++i) {
            a[i] += p0 * (float)w0[i];
            b[i] += p1 * (float)w1[i];
            a[i] += p2 * (float)w2[i];
            b[i] += p3 * (float)w3[i];
        }
    }
    for (; j + 4 <= end; j += 4) {          // 4 edges
        int jj0 = j + sub, jj1 = j + 2 + sub;
        int   d0 = sorted_dst[jj0], d1 = sorted_dst[jj1];
        float p0 = pa[jj0], p1 = pa[jj1];
        bf16x8 w0 = *(const bf16x8*)(Wh + (size_t)d0*F + c);
        bf16x8 w1 = *(const bf16x8*)(Wh + (size_t)d1*F + c);
        #pragma unroll
        for (int i = 0; i < 8; ++i) {
            a[i] += p0 * (float)w0[i];
            b[i] += p1 * (float)w1[i];
        }
    }
    for (; j < end; j += 2) {               // tail: <=3 edges, p=0 padding
        int jj = j + sub;
        int jc = (jj < end) ? jj : (end - 1);
        float p = (jj < end) ? pa[jc] : 0.f;
        int   d = sorted_dst[jc];
        bf16x8 w = *(const bf16x8*)(Wh + (size_t)d*F + c);
        #pragma unroll
        for (int i = 0; i < 8; ++i) a[i] += p * (float)w[i];
    }
    float inv = dinv[n*2 + h];
    #pragma unroll
    for (int i = 0; i < 8; ++i) {
        a[i] += b[i];
        a[i] += __shfl_xor(a[i], 32);       // merge odd-slot partial
    }
    if (sub == 0) {
        f32x4 o0, o1;
        #pragma unroll
        for (int i = 0; i < 4; ++i) { o0[i] = a[i] * inv; o1[i] = a[4+i] * inv; }
        *(f32x4*)(out + (size_t)n*F + c)     = o0;
        *(f32x4*)(out + (size_t)n*F + c + 4) = o1;
    }
}

// ---------------- launch ----------------
extern "C" void kernel_launch(void* const* d_in, const int* in_sizes, int n_in,
                              void* d_out, int out_size, void* d_ws, size_t ws_size,
                              hipStream_t stream) {
    const float* x  = (const float*)d_in[0];
    const int*   ei = (const int*)d_in[1];
    const float* Ww = (const float*)d_in[2];
    const float* Wb = (const float*)d_in[3];
    const float* a  = (const float*)d_in[4];
    float* out = (float*)d_out;
    const int* src = ei;              // edge_index[0]
    const int* dst = ei + N_EDGES;    // edge_index[1]

    // workspace layout (~38 MB), 16B-aligned slices
    char* ws = (char*)d_ws;
    bf16*  Wh        = (bf16*)ws;   ws += (size_t)N_NODES * F * 2;       // 25.6 MB
    bf16*  Wt        = (bf16*)ws;   ws += (size_t)IN_DIM * F * 2;        // 128 KB
    float* s_arr     = (float*)ws;  ws += (size_t)N_NODES * 2 * 4;
    float* t_arr     = (float*)ws;  ws += (size_t)N_NODES * 2 * 4;
    int*   deg       = (int*)ws;    ws += (size_t)N_NODES * 4;
    int*   incl      = (int*)ws;    ws += (size_t)N_NODES * 4;
    int*   bsum      = (int*)ws;    ws += 64 * 4;
    int*   boff      = (int*)ws;    ws += 64 * 4;
    int*   row_start = (int*)ws;    ws += (size_t)(N_NODES + 1) * 4 + 12; // pad to 16B
    int*   cursor    = (int*)ws;    ws += (size_t)N_NODES * 4;
    int*   sdst      = (int*)ws;    ws += (size_t)N_EDGES * 4;           // 3.2 MB
    float* palpha    = (float*)ws;  ws += (size_t)2 * N_EDGES * 4;       // 6.4 MB
    float* dinv      = (float*)ws;  ws += (size_t)N_NODES * 2 * 4;

    k_transpose<<<IN_DIM, F, 0, stream>>>(Ww, Wt, deg);
    k_gemm<<<(N_NODES + 63) / 64, 256, 0, stream>>>(x, Wt, Wb, Wh);
    k_st<<<N_NODES / 4, 256, 0, stream>>>(Wh, a, s_arr, t_arr);
    k_hist<<<(N_EDGES + 255) / 256, 256, 0, stream>>>(src, deg);
    k_scan_local<<<N_SB, SCAN_B, 0, stream>>>(deg, incl, bsum);
    k_scan_block<<<1, 64, 0, stream>>>(bsum, boff, row_start);
    k_scan_final<<<(N_NODES + 255) / 256, 256, 0, stream>>>(incl, deg, boff, row_start, cursor);
    k_scatter<<<(N_EDGES + 255) / 256, 256, 0, stream>>>(src, dst, cursor, sdst);
    k_alpha<<<N_NODES / 4, 256, 0, stream>>>(s_arr, t_arr, row_start, sdst, palpha, dinv);
    k_agg2<<<N_NODES / 4, 256, 0, stream>>>(Wh, palpha, dinv, row_start, sdst, out);
}

// Round 8
// 285.556 us; speedup vs baseline: 1.0783x; 1.0783x over previous
//
#include <hip/hip_runtime.h>
#include <hip/hip_bf16.h>
#include <math.h>

#define N_NODES 50000
#define IN_DIM 256
#define OUT_DIM 128
#define NUM_HEADS 2
#define N_EDGES 800000
#define F (OUT_DIM*NUM_HEADS)   /* 256 */
#define SCAN_B 1024
#define N_SB ((N_NODES + SCAN_B - 1) / SCAN_B)   /* 49 */
#define LDSP 264                 /* 256 + 8 pad */

typedef __bf16 bf16;
typedef __bf16 bf16x8 __attribute__((ext_vector_type(8)));
typedef __bf16 bf16x4 __attribute__((ext_vector_type(4)));
typedef float  f32x4  __attribute__((ext_vector_type(4)));

// ---------------- K0: W -> Wt (bf16, transposed) + zero deg --------------
__global__ void k_transpose(const float* __restrict__ W, bf16* __restrict__ Wt,
                            int* __restrict__ deg) {
    int k = blockIdx.x;      // 0..IN_DIM-1
    int n = threadIdx.x;     // 0..F-1
    Wt[(size_t)n*IN_DIM + k] = (bf16)W[(size_t)k*F + n];
    int id = blockIdx.x * F + threadIdx.x;
    if (id < N_NODES) deg[id] = 0;
}

// ---------------- K1: Wh = x @ W + b, fused s,t  (MFMA bf16) -------------
// Block: 64 rows x 256 cols, 4 waves. Full-K LDS A-tile, one staging barrier.
// Epilogue also computes s[n,h]=Wh·a_src, t[n,h]=Wh·a_dst (kills k_st).
__global__ __launch_bounds__(256) void k_gemm(const float* __restrict__ X,
                                              const bf16* __restrict__ Wt,
                                              const float* __restrict__ Wb,
                                              const float* __restrict__ Av,
                                              bf16* __restrict__ Wh,
                                              float* __restrict__ s_arr,
                                              float* __restrict__ t_arr) {
    __shared__ bf16 As[64 * LDSP];
    __shared__ float sS[2][64], sT[2][64];
    int t = threadIdx.x;
    int wave = t >> 6, lane = t & 63;
    int quad = lane >> 4, l16 = lane & 15;
    int row0 = blockIdx.x * 64;
    int col0 = wave * 64;
    int h = wave >> 1;                       // head of this wave's columns

    // staging: thread t, chunk i: row = 8i + (t>>5), cols (t&31)*8..+8
    {
        int rr = t >> 5;
        int cc = (t & 31) * 8;
        #pragma unroll
        for (int i = 0; i < 8; ++i) {
            int r = row0 + 8*i + rr;
            r = (r < N_NODES) ? r : (N_NODES - 1);
            const float* p = X + (size_t)r * IN_DIM + cc;
            f32x4 lo = *(const f32x4*)p;
            f32x4 hi = *(const f32x4*)(p + 4);
            bf16x8 pk;
            #pragma unroll
            for (int q = 0; q < 4; ++q) {
                pk[q]   = (bf16)lo[q];
                pk[q+4] = (bf16)hi[q];
            }
            *(bf16x8*)(As + (8*i + rr) * LDSP + cc) = pk;
        }
    }
    if (t < 128) { sS[t >> 6][t & 63] = 0.f; sT[t >> 6][t & 63] = 0.f; }
    __syncthreads();

    f32x4 acc[4][4] = {};
    #pragma unroll
    for (int ks = 0; ks < 8; ++ks) {
        int kb = ks * 32;
        bf16x8 bfrag[4];
        #pragma unroll
        for (int ni = 0; ni < 4; ++ni)
            bfrag[ni] = *(const bf16x8*)(Wt + (size_t)(col0 + ni*16 + l16)*IN_DIM
                                            + kb + quad*8);
        bf16x8 afrag[4];
        #pragma unroll
        for (int mi = 0; mi < 4; ++mi)
            afrag[mi] = *(const bf16x8*)(As + (mi*16 + l16)*LDSP + kb + quad*8);

        #pragma unroll
        for (int mi = 0; mi < 4; ++mi)
            #pragma unroll
            for (int ni = 0; ni < 4; ++ni)
                acc[mi][ni] = __builtin_amdgcn_mfma_f32_16x16x32_bf16(
                                  afrag[mi], bfrag[ni], acc[mi][ni], 0, 0, 0);
    }

    // per-lane attention coefficients for this wave's 4 column groups
    float bias_l[4], as_l[4], at_l[4];
    #pragma unroll
    for (int ni = 0; ni < 4; ++ni) {
        int c = col0 + ni*16 + l16;
        int d = c & (OUT_DIM - 1);
        bias_l[ni] = Wb[c];
        as_l[ni]   = Av[d];
        at_l[ni]   = Av[OUT_DIM + d];
    }

    // epilogue: C/D layout col = lane&15, row = quad*4 + reg
    #pragma unroll
    for (int mi = 0; mi < 4; ++mi) {
        #pragma unroll
        for (int reg = 0; reg < 4; ++reg) {
            int rl  = mi*16 + quad*4 + reg;     // local row
            int row = row0 + rl;
            float ps = 0.f, pt = 0.f;
            #pragma unroll
            for (int ni = 0; ni < 4; ++ni) {
                float val = acc[mi][ni][reg] + bias_l[ni];
                if (row < N_NODES)
                    Wh[(size_t)row*F + col0 + ni*16 + l16] = (bf16)val;
                ps += val * as_l[ni];
                pt += val * at_l[ni];
            }
            #pragma unroll
            for (int m = 8; m >= 1; m >>= 1) {  // reduce over 16-lane col group
                ps += __shfl_xor(ps, m);
                pt += __shfl_xor(pt, m);
            }
            if ((lane & 15) == 0) {
                atomicAdd(&sS[h][rl], ps);
                atomicAdd(&sT[h][rl], pt);
            }
        }
    }
    __syncthreads();
    if (t < 128) {
        int hh = t >> 6, rl = t & 63;
        int n = row0 + rl;
        if (n < N_NODES) {
            s_arr[n*2 + hh] = sS[hh][rl];
            t_arr[n*2 + hh] = sT[hh][rl];
        }
    }
}

// ---------------- K3: degree histogram over src ----------------
__global__ void k_hist(const int* __restrict__ src, int* __restrict__ deg) {
    int e = blockIdx.x * 256 + threadIdx.x;
    if (e < N_EDGES) atomicAdd(&deg[src[e]], 1);
}

// ---------------- K4a: per-block inclusive scan ----------------
__global__ __launch_bounds__(SCAN_B) void k_scan_local(const int* __restrict__ deg,
                                                       int* __restrict__ incl,
                                                       int* __restrict__ bsum) {
    __shared__ int lds[SCAN_B];
    int t = threadIdx.x;
    int i = blockIdx.x * SCAN_B + t;
    int v = (i < N_NODES) ? deg[i] : 0;
    lds[t] = v;
    __syncthreads();
    for (int off = 1; off < SCAN_B; off <<= 1) {
        int u = (t >= off) ? lds[t - off] : 0;
        __syncthreads();
        lds[t] += u;
        __syncthreads();
    }
    if (i < N_NODES) incl[i] = lds[t];
    if (t == SCAN_B - 1) bsum[blockIdx.x] = lds[t];
}

// ---------------- K4b: finalize exclusive scan (folds block-sum scan) ----
__global__ __launch_bounds__(256) void k_scan_final(const int* __restrict__ incl,
                                                    const int* __restrict__ deg,
                                                    const int* __restrict__ bsum,
                                                    int* __restrict__ row_start,
                                                    int* __restrict__ cursor) {
    __shared__ int sboff[64];
    int t = threadIdx.x;
    if (t < 64) {                    // redundant per-block scan of 49 sums
        int orig = (t < N_SB) ? bsum[t] : 0;
        int v = orig;
        #pragma unroll
        for (int off = 1; off < 64; off <<= 1) {
            int u = __shfl_up(v, off);
            if (t >= off) v += u;
        }
        sboff[t] = v - orig;
        if (t == 63 && blockIdx.x == 0) row_start[N_NODES] = v;
    }
    __syncthreads();
    int i = blockIdx.x * 256 + t;
    if (i < N_NODES) {
        int excl = incl[i] - deg[i] + sboff[i >> 10];
        row_start[i] = excl;
        cursor[i]    = excl;
    }
}

// ---------------- K5: scatter edges into CSR slots (grouped by src) ------
__global__ void k_scatter(const int* __restrict__ src, const int* __restrict__ dst,
                          int* __restrict__ cursor, int* __restrict__ sorted_dst) {
    int e = blockIdx.x * 256 + threadIdx.x;
    if (e < N_EDGES) {
        int s = src[e];
        int pos = atomicAdd(&cursor[s], 1);
        sorted_dst[pos] = dst[e];
    }
}

// ---------------- K6a: per-edge softmax weights, both heads --------------
// half-wave (32 lanes) per node; lanes parallel over edges; float2 t gather.
__global__ __launch_bounds__(256) void k_alpha(const float* __restrict__ s_arr,
                                               const float* __restrict__ t_arr,
                                               const int* __restrict__ row_start,
                                               const int* __restrict__ sdst,
                                               float* __restrict__ palpha,
                                               float* __restrict__ dinv) {
    int wave = threadIdx.x >> 6, lane = threadIdx.x & 63;
    int half = lane >> 5, sl = lane & 31;
    int n = blockIdx.x * 8 + wave * 2 + half;
    int beg = row_start[n], end = row_start[n + 1];
    int deg = end - beg;
    if (deg == 0) return;
    float2 sv = ((const float2*)s_arr)[n];

    float e0c = -INFINITY, e1c = -INFINITY;
    if (sl < deg) {
        int d = sdst[beg + sl];
        float2 tv = ((const float2*)t_arr)[d];
        float e0 = sv.x + tv.x, e1 = sv.y + tv.y;
        e0c = (e0 >= 0.f) ? e0 : 0.2f * e0;
        e1c = (e1 >= 0.f) ? e1 : 0.2f * e1;
    }
    float mx0 = e0c, mx1 = e1c;
    for (int j0 = 32; j0 < deg; j0 += 32) {
        int jj = j0 + sl;
        if (jj < deg) {
            int d = sdst[beg + jj];
            float2 tv = ((const float2*)t_arr)[d];
            float e0 = sv.x + tv.x, e1 = sv.y + tv.y;
            e0 = (e0 >= 0.f) ? e0 : 0.2f * e0;
            e1 = (e1 >= 0.f) ? e1 : 0.2f * e1;
            mx0 = fmaxf(mx0, e0);
            mx1 = fmaxf(mx1, e1);
        }
    }
    #pragma unroll
    for (int m = 16; m >= 1; m >>= 1) {     // masks <32 stay in half-wave
        mx0 = fmaxf(mx0, __shfl_xor(mx0, m));
        mx1 = fmaxf(mx1, __shfl_xor(mx1, m));
    }

    float p0 = (sl < deg) ? __expf(e0c - mx0) : 0.f;
    float p1 = (sl < deg) ? __expf(e1c - mx1) : 0.f;
    if (sl < deg) {
        palpha[beg + sl]           = p0;
        palpha[N_EDGES + beg + sl] = p1;
    }
    float sum0 = p0, sum1 = p1;
    for (int j0 = 32; j0 < deg; j0 += 32) {
        int jj = j0 + sl;
        if (jj < deg) {
            int d = sdst[beg + jj];
            float2 tv = ((const float2*)t_arr)[d];
            float e0 = sv.x + tv.x, e1 = sv.y + tv.y;
            e0 = (e0 >= 0.f) ? e0 : 0.2f * e0;
            e1 = (e1 >= 0.f) ? e1 : 0.2f * e1;
            float q0 = __expf(e0 - mx0);
            float q1 = __expf(e1 - mx1);
            palpha[beg + jj]           = q0;
            palpha[N_EDGES + beg + jj] = q1;
            sum0 += q0;
            sum1 += q1;
        }
    }
    #pragma unroll
    for (int m = 16; m >= 1; m >>= 1) {
        sum0 += __shfl_xor(sum0, m);
        sum1 += __shfl_xor(sum1, m);
    }
    if (sl == 0) {
        dinv[n*2]     = 1.f / sum0;
        dinv[n*2 + 1] = 1.f / sum1;
    }
}

// ---------------- K6b: gather+FMA aggregation, 8 edges/iter --------------
__global__ __launch_bounds__(256) void k_agg2(const bf16* __restrict__ Wh,
                                              const float* __restrict__ palpha,
                                              const float* __restrict__ dinv,
                                              const int* __restrict__ row_start,
                                              const int* __restrict__ sorted_dst,
                                              float* __restrict__ out) {
    int wave = threadIdx.x >> 6, lane = threadIdx.x & 63;
    int n = blockIdx.x * 4 + wave;
    int sub = lane >> 5;
    int cl  = lane & 31;
    int c   = cl * 8;
    int h   = c >> 7;
    int beg = row_start[n], end = row_start[n + 1];
    if (beg == end) {
        if (sub == 0) {
            bf16x8 wh = *(const bf16x8*)(Wh + (size_t)n*F + c);
            f32x4 o0, o1;
            #pragma unroll
            for (int i = 0; i < 4; ++i) { o0[i] = (float)wh[i]; o1[i] = (float)wh[4+i]; }
            *(f32x4*)(out + (size_t)n*F + c)     = o0;
            *(f32x4*)(out + (size_t)n*F + c + 4) = o1;
        }
        return;
    }
    const float* pa = palpha + (size_t)h * N_EDGES;
    float a[8] = {0,0,0,0,0,0,0,0};
    float b[8] = {0,0,0,0,0,0,0,0};
    int j = beg;
    for (; j + 8 <= end; j += 8) {
        int   jj0 = j + sub,     jj1 = j + 2 + sub;
        int   jj2 = j + 4 + sub, jj3 = j + 6 + sub;
        int   d0 = sorted_dst[jj0], d1 = sorted_dst[jj1];
        int   d2 = sorted_dst[jj2], d3 = sorted_dst[jj3];
        float p0 = pa[jj0], p1 = pa[jj1], p2 = pa[jj2], p3 = pa[jj3];
        bf16x8 w0 = *(const bf16x8*)(Wh + (size_t)d0*F + c);
        bf16x8 w1 = *(const bf16x8*)(Wh + (size_t)d1*F + c);
        bf16x8 w2 = *(const bf16x8*)(Wh + (size_t)d2*F + c);
        bf16x8 w3 = *(const bf16x8*)(Wh + (size_t)d3*F + c);
        #pragma unroll
        for (int i = 0; i < 8; ++i) {
            a[i] += p0 * (float)w0[i];
            b[i] += p1 * (float)w1[i];
            a[i] += p2 * (float)w2[i];
            b[i] += p3 * (float)w3[i];
        }
    }
    for (; j + 4 <= end; j += 4) {
        int jj0 = j + sub, jj1 = j + 2 + sub;
        int   d0 = sorted_dst[jj0], d1 = sorted_dst[jj1];
        float p0 = pa[jj0], p1 = pa[jj1];
        bf16x8 w0 = *(const bf16x8*)(Wh + (size_t)d0*F + c);
        bf16x8 w1 = *(const bf16x8*)(Wh + (size_t)d1*F + c);
        #pragma unroll
        for (int i = 0; i < 8; ++i) {
            a[i] += p0 * (float)w0[i];
            b[i] += p1 * (float)w1[i];
        }
    }
    for (; j < end; j += 2) {
        int jj = j + sub;
        int jc = (jj < end) ? jj : (end - 1);
        float p = (jj < end) ? pa[jc] : 0.f;
        int   d = sorted_dst[jc];
        bf16x8 w = *(const bf16x8*)(Wh + (size_t)d*F + c);
        #pragma unroll
        for (int i = 0; i < 8; ++i) a[i] += p * (float)w[i];
    }
    float inv = dinv[n*2 + h];
    #pragma unroll
    for (int i = 0; i < 8; ++i) {
        a[i] += b[i];
        a[i] += __shfl_xor(a[i], 32);
    }
    if (sub == 0) {
        f32x4 o0, o1;
        #pragma unroll
        for (int i = 0; i < 4; ++i) { o0[i] = a[i] * inv; o1[i] = a[4+i] * inv; }
        *(f32x4*)(out + (size_t)n*F + c)     = o0;
        *(f32x4*)(out + (size_t)n*F + c + 4) = o1;
    }
}

// ---------------- launch ----------------
extern "C" void kernel_launch(void* const* d_in, const int* in_sizes, int n_in,
                              void* d_out, int out_size, void* d_ws, size_t ws_size,
                              hipStream_t stream) {
    const float* x  = (const float*)d_in[0];
    const int*   ei = (const int*)d_in[1];
    const float* Ww = (const float*)d_in[2];
    const float* Wb = (const float*)d_in[3];
    const float* a  = (const float*)d_in[4];
    float* out = (float*)d_out;
    const int* src = ei;              // edge_index[0]
    const int* dst = ei + N_EDGES;    // edge_index[1]

    // workspace layout (~38 MB), 16B-aligned slices
    char* ws = (char*)d_ws;
    bf16*  Wh        = (bf16*)ws;   ws += (size_t)N_NODES * F * 2;       // 25.6 MB
    bf16*  Wt        = (bf16*)ws;   ws += (size_t)IN_DIM * F * 2;        // 128 KB
    float* s_arr     = (float*)ws;  ws += (size_t)N_NODES * 2 * 4;
    float* t_arr     = (float*)ws;  ws += (size_t)N_NODES * 2 * 4;
    int*   deg       = (int*)ws;    ws += (size_t)N_NODES * 4;
    int*   incl      = (int*)ws;    ws += (size_t)N_NODES * 4;
    int*   bsum      = (int*)ws;    ws += 64 * 4;
    int*   row_start = (int*)ws;    ws += (size_t)(N_NODES + 1) * 4 + 12; // pad to 16B
    int*   cursor    = (int*)ws;    ws += (size_t)N_NODES * 4;
    int*   sdst      = (int*)ws;    ws += (size_t)N_EDGES * 4;           // 3.2 MB
    float* palpha    = (float*)ws;  ws += (size_t)2 * N_EDGES * 4;       // 6.4 MB
    float* dinv      = (float*)ws;  ws += (size_t)N_NODES * 2 * 4;

    k_transpose<<<IN_DIM, F, 0, stream>>>(Ww, Wt, deg);
    k_gemm<<<(N_NODES + 63) / 64, 256, 0, stream>>>(x, Wt, Wb, a, Wh, s_arr, t_arr);
    k_hist<<<(N_EDGES + 255) / 256, 256, 0, stream>>>(src, deg);
    k_scan_local<<<N_SB, SCAN_B, 0, stream>>>(deg, incl, bsum);
    k_scan_final<<<(N_NODES + 255) / 256, 256, 0, stream>>>(incl, deg, bsum, row_start, cursor);
    k_scatter<<<(N_EDGES + 255) / 256, 256, 0, stream>>>(src, dst, cursor, sdst);
    k_alpha<<<N_NODES / 8, 256, 0, stream>>>(s_arr, t_arr, row_start, sdst, palpha, dinv);
    k_agg2<<<N_NODES / 4, 256, 0, stream>>>(Wh, palpha, dinv, row_start, sdst, out);
}